// Round 14
// baseline (312.040 us; speedup 1.0000x reference)
//
#include <hip/hip_runtime.h>
#include <math.h>

typedef unsigned short u16;
typedef __attribute__((ext_vector_type(8))) short bf16x8;
typedef __attribute__((ext_vector_type(4))) float f32x4;

#define S_VALID 1500
#define S_PAD   1536
#define DMODEL  1280
#define NHEAD   20
#define HDIM    64
#define FFND    5120
#define ZKEYS   768      // keys per KV-split half
#define NSPLIT_TILES 12  // 768 / 64

__device__ __forceinline__ u16 f2bf(float f) {
  union { float f; unsigned u; } v; v.f = f;
  unsigned r = v.u + 0x7fffu + ((v.u >> 16) & 1u);  // RNE
  return (u16)(r >> 16);
}
__device__ __forceinline__ float bf2f(u16 h) {
  union { unsigned u; float f; } v; v.u = ((unsigned)h) << 16; return v.f;
}

template <int N>
__device__ __forceinline__ void wait_vmcnt() {
  if constexpr (N == 8)      asm volatile("s_waitcnt vmcnt(8)"  ::: "memory");
  else if constexpr (N == 6) asm volatile("s_waitcnt vmcnt(6)"  ::: "memory");
  else if constexpr (N == 5) asm volatile("s_waitcnt vmcnt(5)"  ::: "memory");
  else if constexpr (N == 4) asm volatile("s_waitcnt vmcnt(4)"  ::: "memory");
  else if constexpr (N == 3) asm volatile("s_waitcnt vmcnt(3)"  ::: "memory");
  else if constexpr (N == 2) asm volatile("s_waitcnt vmcnt(2)"  ::: "memory");
  else if constexpr (N == 1) asm volatile("s_waitcnt vmcnt(1)"  ::: "memory");
  else                       asm volatile("s_waitcnt vmcnt(0)"  ::: "memory");
}
__device__ __forceinline__ void wait_lgkm0() {
  asm volatile("s_waitcnt lgkmcnt(0)" ::: "memory");
}

// ---------------- LayerNorm (fp32 in -> bf16 out, rows padded) ----------------
__global__ __launch_bounds__(256) void k_ln(const float* __restrict__ x,
                                            const float* __restrict__ w,
                                            const float* __restrict__ b,
                                            u16* __restrict__ out, int rows_valid) {
  int r = blockIdx.x;
  int t = threadIdx.x;
  if (r >= rows_valid) {
    for (int i = t; i < DMODEL; i += 256) out[r * DMODEL + i] = 0;
    return;
  }
  const float* xr = x + (size_t)r * DMODEL;
  float vals[5]; float s = 0.f, ss = 0.f;
#pragma unroll
  for (int j = 0; j < 5; ++j) {
    float v = xr[t + j * 256]; vals[j] = v; s += v; ss += v * v;
  }
#pragma unroll
  for (int m = 1; m < 64; m <<= 1) { s += __shfl_xor(s, m); ss += __shfl_xor(ss, m); }
  __shared__ float ps[4], pss[4];
  int lane = t & 63, wv = t >> 6;
  if (lane == 0) { ps[wv] = s; pss[wv] = ss; }
  __syncthreads();
  s = ps[0] + ps[1] + ps[2] + ps[3];
  ss = pss[0] + pss[1] + pss[2] + pss[3];
  float mean = s * (1.f / DMODEL);
  float var = ss * (1.f / DMODEL) - mean * mean;
  float rstd = rsqrtf(var + 1e-5f);
#pragma unroll
  for (int j = 0; j < 5; ++j) {
    int i = t + j * 256;
    out[r * DMODEL + i] = f2bf(w[i] * ((vals[j] - mean) * rstd) + b[i]);
  }
}

// ---------------- GEMM  C[m,n] = sum_k A[m,k]*B[n,k] ------------------------
// A: bf16 workspace (global_load_lds staging, swizzled — verified path).
// B: fp32 USER WEIGHTS, reg-staged (load fp32 -> cvt bf16 -> ds_write) into the
//    byte-identical swizzled LDS image the old path produced. T14 split: issue
//    loads early, write after compute. Saves the whole cvt pass (~19us HBM).
struct EpiParams {
  const float* bias;
  float* outf;
  u16* outb;
  u16* q; u16* k; u16* vt;
  const float* qb; const float* vb;
  const float* wq_; const float* wk_; const float* wv_;  // QKV weight select
  const float* w0_;                                       // single weight base
  int mvalid;
};

template <int ROWS, int NT>
__device__ __forceinline__ void stage_tileA(const u16* __restrict__ g, int ld,
                                            u16* lds, int t) {
  constexpr int ITERS = ROWS * 128 / (NT * 16);   // 128 B per row (BK=64 bf16)
#pragma unroll
  for (int i = 0; i < ITERS; ++i) {
    int off = i * (NT * 16) + t * 16;
    int row = off >> 7;
    int sp  = (off >> 4) & 7;
    int s   = sp ^ (row & 7);
    const u16* gp = g + row * ld + s * 8;
    u16* lp = lds + i * (NT * 8) + ((t >> 6) << 9);
    __builtin_amdgcn_global_load_lds((const __attribute__((address_space(1))) void*)gp,
                                     (__attribute__((address_space(3))) void*)lp,
                                     16, 0, 0);
  }
}

__device__ __forceinline__ bf16x8 ld_frag(const u16* lds, int row, int kk, int lane) {
  int slot = kk * 4 + (lane >> 4);
  int sp = slot ^ (row & 7);
  return *(const bf16x8*)(lds + row * 64 + sp * 8);
}

// Shared GEMM body. NTH=threads, WN=waves in N dim (WM = NTH/64/WN).
template <int BM, int BN, int NTH, int WM, int WN, int EPI>
__device__ __forceinline__ void gemm_body(const u16* __restrict__ A,
                                          int N, int K, int lda, int ldb,
                                          const EpiParams& ep,
                                          u16* lds_a0, u16* lds_a1,
                                          u16* lds_b0, u16* lds_b1) {
  constexpr int FM = BM / (32 * WM) * 2, FN = BN / (32 * WN) * 2;  // 16-frag counts
  constexpr int AL = BM * 128 / (NTH * 16);        // A gloads per thread per stage
  u16* lds_a[2] = { lds_a0, lds_a1 };
  u16* lds_b[2] = { lds_b0, lds_b1 };
  const int t = threadIdx.x, lane = t & 63, wid = t >> 6;
  const int wm = wid / WN, wn = wid % WN;

  unsigned nwg = gridDim.x * gridDim.y;
  unsigned bid = blockIdx.y * gridDim.x + blockIdx.x;
  unsigned cpx = nwg >> 3;
  bid = (bid & 7u) * cpx + (bid >> 3);
  const int bm0 = (bid % gridDim.x) * BM, bn0 = (bid / gridDim.x) * BN;

  const int l15 = lane & 15, g4 = lane >> 4;

  f32x4 acc[FM][FN] = {};
  const size_t zk = (EPI == 4) ? (size_t)blockIdx.z * K : 0;
  const u16* Ab = A + (size_t)bm0 * lda + zk;

  // B fp32 source base
  const float* Bf;
  if constexpr (EPI == 0) {
    int sel = bn0 / DMODEL;
    int rem = bn0 - sel * DMODEL;
    Bf = (sel == 0 ? ep.wq_ : sel == 1 ? ep.wk_ : ep.wv_) + (size_t)rem * ldb;
  } else {
    Bf = ep.w0_ + (size_t)bn0 * ldb + zk;
  }

  // per-thread B chunk mapping: 2 iters x 16B bf16 (= 8 fp32)
  int brow[2], bs[2];
#pragma unroll
  for (int i = 0; i < 2; ++i) {
    int off = i * (NTH * 16) + t * 16;
    int row = off >> 7, sp = (off >> 4) & 7;
    brow[i] = row; bs[i] = sp ^ (row & 7);
  }
  float4 br[2][2];

  auto issueB = [&](int kt) {
#pragma unroll
    for (int i = 0; i < 2; ++i) {
      const float* gp = Bf + (size_t)brow[i] * ldb + kt * 64 + bs[i] * 8;
      br[i][0] = *(const float4*)gp;
      br[i][1] = *(const float4*)(gp + 4);
    }
  };
  auto writeB = [&](int buf) {
#pragma unroll
    for (int i = 0; i < 2; ++i) {
      union { u16 s[8]; bf16x8 v; } pk;
      const float* f0 = (const float*)&br[i][0];
      const float* f1 = (const float*)&br[i][1];
#pragma unroll
      for (int j = 0; j < 4; ++j) { pk.s[j] = f2bf(f0[j]); pk.s[4 + j] = f2bf(f1[j]); }
      *(bf16x8*)(lds_b[buf] + i * (NTH * 8) + t * 8) = pk.v;
    }
  };

  const int NT = K >> 6;
  issueB(0);
  stage_tileA<BM, NTH>(Ab, lda, lds_a[0], t);
  wait_vmcnt<AL>();                    // B0 regs ready (oldest); A0 in flight
  writeB(0);
  int buf = 0;

  for (int kt = 0; kt < NT; ++kt) {
    if (kt + 1 < NT) {
      issueB(kt + 1);
      stage_tileA<BM, NTH>(Ab + (kt + 1) * 64, lda, lds_a[buf ^ 1], t);
      wait_vmcnt<4 + AL>();            // A(kt) complete; B(kt+1)+A(kt+1) in flight
    } else {
      wait_vmcnt<0>();
    }
    wait_lgkm0();                      // B(kt) ds_writes visible
    __builtin_amdgcn_s_barrier();
    const u16* la = lds_a[buf];
    const u16* lb = lds_b[buf];
#pragma unroll
    for (int kk = 0; kk < 2; ++kk) {
      bf16x8 af[FM], bfr[FN];
#pragma unroll
      for (int i = 0; i < FM; ++i) af[i]  = ld_frag(la, wm * (BM / WM) + i * 16 + l15, kk, lane);
#pragma unroll
      for (int j = 0; j < FN; ++j) bfr[j] = ld_frag(lb, wn * (BN / WN) + j * 16 + l15, kk, lane);
#pragma unroll
      for (int i = 0; i < FM; ++i)
#pragma unroll
        for (int j = 0; j < FN; ++j)
          acc[i][j] = __builtin_amdgcn_mfma_f32_16x16x32_bf16(af[i], bfr[j], acc[i][j], 0, 0, 0);
    }
    if (kt + 1 < NT) {
      wait_vmcnt<AL>();                // B(kt+1) regs ready (A(kt+1) still flying)
      writeB(buf ^ 1);
    }
    wait_lgkm0();
    __builtin_amdgcn_s_barrier();
    buf ^= 1;
  }

#pragma unroll
  for (int i = 0; i < FM; ++i)
#pragma unroll
    for (int j = 0; j < FN; ++j) {
      int n = bn0 + wn * (BN / WN) + j * 16 + l15;
      int mbase = bm0 + wm * (BM / WM) + i * 16 + g4 * 4;
      if constexpr (EPI == 0) {
        if (n >= 2 * DMODEL) {
          int nn = n - 2 * DMODEL;
          union { u16 s[4]; uint2 v2; } pk;
#pragma unroll
          for (int r = 0; r < 4; ++r) {
            int m = mbase + r;
            float val = (m < ep.mvalid) ? (acc[i][j][r] + ep.vb[nn]) : 0.f;
            pk.s[r] = f2bf(val);
          }
          *(uint2*)(ep.vt + (size_t)nn * S_PAD + mbase) = pk.v2;
        } else {
#pragma unroll
          for (int r = 0; r < 4; ++r) {
            int m = mbase + r;
            float v = acc[i][j][r];
            if (n < DMODEL) {
              float val = (m < ep.mvalid) ? (v + ep.qb[n]) * 0.125f : 0.f;
              ep.q[m * DMODEL + n] = f2bf(val);
            } else {
              int nn = n - DMODEL;
              ep.k[m * DMODEL + nn] = f2bf(m < ep.mvalid ? v : 0.f);
            }
          }
        }
      } else {
#pragma unroll
        for (int r = 0; r < 4; ++r) {
          int m = mbase + r;
          float v = acc[i][j][r];
          if constexpr (EPI == 2) {
            float xx = v + ep.bias[n];
            float gg = 0.5f * xx * (1.f + erff(xx * 0.70710678118f));
            ep.outb[(size_t)m * N + n] = f2bf(gg);
          } else if constexpr (EPI == 4) {
            ep.outf[((size_t)blockIdx.z * S_PAD + m) * DMODEL + n] = v;
          }
        }
      }
    }
}

// 512-thread, 8-wave (2M x 4N), 64x128 tile — QKV / O-proj.
template <int BM, int BN, int EPI>
__global__ __launch_bounds__(512) void k_gemm(const u16* __restrict__ A,
                                              int N, int K, int lda, int ldb,
                                              EpiParams ep) {
  __shared__ __align__(128) u16 lds_a[2][BM * 64];
  __shared__ __align__(128) u16 lds_b[2][BN * 64];
  gemm_body<BM, BN, 512, 2, 4, EPI>(A, N, K, lda, ldb, ep,
                                    &lds_a[0][0], &lds_a[1][0],
                                    &lds_b[0][0], &lds_b[1][0]);
}

// 256-thread, 4-wave (2x2), 64x64 tile — FC1 / FC2.
template <int BM, int BN, int EPI>
__global__ __launch_bounds__(256) void k_gemm2(const u16* __restrict__ A,
                                               int N, int K, int lda, int ldb,
                                               EpiParams ep) {
  __shared__ __align__(128) u16 lds_a[2][BM * 64];
  __shared__ __align__(128) u16 lds_b[2][BN * 64];
  gemm_body<BM, BN, 256, 2, 2, EPI>(A, N, K, lda, ldb, ep,
                                    &lds_a[0][0], &lds_a[1][0],
                                    &lds_b[0][0], &lds_b[1][0]);
}

// ---------------- split-K reducer: out = p0 + p1 + bias + resid --------------
__global__ __launch_bounds__(256) void k_red(const float* __restrict__ p,
                                             const float* __restrict__ bias,
                                             const float* __restrict__ resid,
                                             float* __restrict__ out) {
  int idx = blockIdx.x * 256 + threadIdx.x;
  if (idx >= S_VALID * (DMODEL / 4)) return;
  int m = idx / (DMODEL / 4), n4 = (idx % (DMODEL / 4)) * 4;
  float4 a  = *(const float4*)(p + (size_t)m * DMODEL + n4);
  float4 b  = *(const float4*)(p + ((size_t)S_PAD + m) * DMODEL + n4);
  float4 rs = *(const float4*)(resid + (size_t)m * DMODEL + n4);
  float4 bb = *(const float4*)(bias + n4);
  float4 o;
  o.x = a.x + b.x + rs.x + bb.x;
  o.y = a.y + b.y + rs.y + bb.y;
  o.z = a.z + b.z + rs.z + bb.z;
  o.w = a.w + b.w + rs.w + bb.w;
  *(float4*)(out + (size_t)m * DMODEL + n4) = o;
}

// ---- flash attention, split-KV x2, KVBLK=64 (two verified 32-key subtiles) --
__global__ __launch_bounds__(256) void k_attn(const u16* __restrict__ q,
                                              const u16* __restrict__ k,
                                              const u16* __restrict__ vt,
                                              u16* __restrict__ o0,
                                              u16* __restrict__ o1,
                                              float2* __restrict__ ml) {
  __shared__ __align__(128) u16 kls[2][2][2048];
  __shared__ __align__(128) u16 vls[2][2][2048];
  const int t = threadIdx.x;
  const int lane = t & 63, wid = t >> 6;
  const int h = blockIdx.y, z = blockIdx.z;
  const int zb = z * ZKEYS;
  const int qbase = blockIdx.x * 64 + wid * 16;
  const int l15 = lane & 15, g = lane >> 4;

  const int srow = t >> 3;
  const int psl  = t & 7;
  const int slog = psl ^ (srow & 7);
  const int kperm = 8 * ((srow & 15) >> 2) + (srow & 3) + 4 * (srow >> 4);
  const int vd    = 2 * srow + (slog >> 2);
  const int vkoff = (slog & 3) * 8;
  const u16* kbasep = k + (size_t)kperm * DMODEL + h * HDIM + slog * 8;
  const u16* vbasep = vt + (size_t)(h * HDIM + vd) * S_PAD + vkoff;
  const int wbase = (t >> 6) << 9;

  bf16x8 qf[2];
#pragma unroll
  for (int half = 0; half < 2; ++half)
    qf[half] = *(const bf16x8*)(q + (qbase + l15) * DMODEL + h * HDIM + half * 32 + g * 8);

  auto stage = [&](int tt, int buf) {
#pragma unroll
    for (int u = 0; u < 2; ++u) {
      int keyoff = zb + tt * 64 + u * 32;
      __builtin_amdgcn_global_load_lds(
          (const __attribute__((address_space(1))) void*)(kbasep + (size_t)keyoff * DMODEL),
          (__attribute__((address_space(3))) void*)(&kls[buf][u][0] + wbase), 16, 0, 0);
      __builtin_amdgcn_global_load_lds(
          (const __attribute__((address_space(1))) void*)(vbasep + keyoff),
          (__attribute__((address_space(3))) void*)(&vls[buf][u][0] + wbase), 16, 0, 0);
    }
  };

  stage(0, 0);
  int buf = 0;

  float Mx = -1e30f, L = 0.f;
  f32x4 c[4] = {};

  for (int tt = 0; tt < NSPLIT_TILES; ++tt) {
    if (tt + 1 < NSPLIT_TILES) {
      stage(tt + 1, buf ^ 1);
      wait_vmcnt<4>();
    } else {
      wait_vmcnt<0>();
    }
    __builtin_amdgcn_s_barrier();

    f32x4 sc[2][2];
#pragma unroll
    for (int u = 0; u < 2; ++u)
#pragma unroll
      for (int s = 0; s < 2; ++s) {
        int row = 16 * s + l15;
        const u16* kb = &kls[buf][u][0];
        bf16x8 ka0 = *(const bf16x8*)(kb + row * 64 + ((g)     ^ (row & 7)) * 8);
        bf16x8 ka1 = *(const bf16x8*)(kb + row * 64 + ((4 + g) ^ (row & 7)) * 8);
        f32x4 zz = {};
        zz = __builtin_amdgcn_mfma_f32_16x16x32_bf16(ka0, qf[0], zz, 0, 0, 0);
        zz = __builtin_amdgcn_mfma_f32_16x16x32_bf16(ka1, qf[1], zz, 0, 0, 0);
        sc[u][s] = zz;
      }
    float pm = -1e30f;
#pragma unroll
    for (int u = 0; u < 2; ++u)
#pragma unroll
      for (int s = 0; s < 2; ++s)
#pragma unroll
        for (int r = 0; r < 4; ++r) {
          int kg = zb + tt * 64 + u * 32 + 8 * g + 4 * s + r;
          float v = (kg < S_VALID) ? sc[u][s][r] : -1e30f;
          sc[u][s][r] = v;
          pm = fmaxf(pm, v);
        }
    pm = fmaxf(pm, __shfl_xor(pm, 16));
    pm = fmaxf(pm, __shfl_xor(pm, 32));
    float Mn = fmaxf(Mx, pm);
    float fac = __expf(Mx - Mn);
    float p[2][8]; float rs = 0.f;
#pragma unroll
    for (int u = 0; u < 2; ++u)
#pragma unroll
      for (int s = 0; s < 2; ++s)
#pragma unroll
        for (int r = 0; r < 4; ++r) {
          float e = __expf(sc[u][s][r] - Mn);
          p[u][4 * s + r] = e; rs += e;
        }
    rs += __shfl_xor(rs, 16);
    rs += __shfl_xor(rs, 32);
    L = L * fac + rs; Mx = Mn;

    float facr[4];
#pragma unroll
    for (int r = 0; r < 4; ++r) facr[r] = __shfl(fac, g * 20 + r);
#pragma unroll
    for (int ch = 0; ch < 4; ++ch)
#pragma unroll
      for (int r = 0; r < 4; ++r) c[ch][r] *= facr[r];

    bf16x8 pa[2];
#pragma unroll
    for (int u = 0; u < 2; ++u)
#pragma unroll
      for (int j = 0; j < 8; ++j) pa[u][j] = (short)f2bf(p[u][j]);
#pragma unroll
    for (int ch = 0; ch < 4; ++ch) {
      int R = 8 * ch + (l15 >> 1);
      int sl = (l15 & 1) * 4 + g;
#pragma unroll
      for (int u = 0; u < 2; ++u) {
        bf16x8 vbf = *(const bf16x8*)(&vls[buf][u][0] + R * 64 + (sl ^ (R & 7)) * 8);
        c[ch] = __builtin_amdgcn_mfma_f32_16x16x32_bf16(pa[u], vbf, c[ch], 0, 0, 0);
      }
    }
    __builtin_amdgcn_s_barrier();
    buf ^= 1;
  }

  u16* op = z ? o1 : o0;
  if (g == 0) ml[(size_t)(z * NHEAD + h) * S_PAD + qbase + l15] = make_float2(Mx, L);
#pragma unroll
  for (int ch = 0; ch < 4; ++ch)
#pragma unroll
    for (int r = 0; r < 4; ++r) {
      int m = qbase + g * 4 + r;
      op[(size_t)m * DMODEL + h * HDIM + ch * 16 + l15] = f2bf(c[ch][r]);
    }
}

// ---------------- combine the two KV halves (exact fp32 LSE merge) -----------
__global__ __launch_bounds__(256) void k_comb(u16* __restrict__ o0,
                                              const u16* __restrict__ o1,
                                              const float2* __restrict__ ml) {
  int idx = blockIdx.x * 256 + threadIdx.x;
  if (idx >= S_VALID * (DMODEL / 4)) return;
  int m = idx / (DMODEL / 4);
  int d = (idx % (DMODEL / 4)) * 4;
  int h = d >> 6;
  float2 a = ml[(size_t)h * S_PAD + m];
  float2 b = ml[(size_t)(NHEAD + h) * S_PAD + m];
  float M = fmaxf(a.x, b.x);
  float w0 = __expf(a.x - M), w1 = __expf(b.x - M);
  float inv = 1.f / (w0 * a.y + w1 * b.y);
  w0 *= inv; w1 *= inv;
  union { u16 s[4]; uint2 v; } A, B, O;
  A.v = *(const uint2*)(o0 + (size_t)m * DMODEL + d);
  B.v = *(const uint2*)(o1 + (size_t)m * DMODEL + d);
#pragma unroll
  for (int j = 0; j < 4; ++j)
    O.s[j] = f2bf(w0 * bf2f(A.s[j]) + w1 * bf2f(B.s[j]));
  *(uint2*)(o0 + (size_t)m * DMODEL + d) = O.v;
}

// ----------------------------------------------------------------------------
extern "C" void kernel_launch(void* const* d_in, const int* in_sizes, int n_in,
                              void* d_out, int out_size, void* d_ws, size_t ws_size,
                              hipStream_t stream) {
  const float* x    = (const float*)d_in[0];
  const float* ln1w = (const float*)d_in[1];
  const float* ln1b = (const float*)d_in[2];
  const float* ln2w = (const float*)d_in[3];
  const float* ln2b = (const float*)d_in[4];
  const float* wq   = (const float*)d_in[5];
  const float* qb   = (const float*)d_in[6];
  const float* wk   = (const float*)d_in[7];
  const float* wv   = (const float*)d_in[8];
  const float* vb   = (const float*)d_in[9];
  const float* wo   = (const float*)d_in[10];
  const float* ob   = (const float*)d_in[11];
  const float* wfc1 = (const float*)d_in[12];
  const float* fb1  = (const float*)d_in[13];
  const float* wfc2 = (const float*)d_in[14];
  const float* fb2  = (const float*)d_in[15];

  char* ws = (char*)d_ws;
  size_t off = 0;
  auto alloc = [&](size_t bytes) {
    void* p = ws + off; off += (bytes + 255) & ~(size_t)255; return p;
  };
  u16*   hbuf  = (u16*)alloc((size_t)S_PAD * DMODEL * 2);
  u16*   qbuf  = (u16*)alloc((size_t)S_PAD * DMODEL * 2);
  u16*   kbuf  = (u16*)alloc((size_t)S_PAD * DMODEL * 2);
  u16*   vtb   = (u16*)alloc((size_t)DMODEL * S_PAD * 2);
  u16*   ctxb  = (u16*)alloc((size_t)S_PAD * DMODEL * 2);
  float* res2  = (float*)alloc((size_t)S_PAD * DMODEL * 4);
  u16*   h2buf = (u16*)alloc((size_t)S_PAD * DMODEL * 2);
  u16*   gbuf  = (u16*)alloc((size_t)S_PAD * FFND * 2);
  float* skp   = (float*)alloc((size_t)2 * S_PAD * DMODEL * 4);   // split-K partials
  u16*    opart1 = (u16*)res2;                 // attn scratch aliases res2 (dead then)
  float2* mlbuf  = (float2*)((char*)res2 + (size_t)S_PAD * DMODEL * 2);
  (void)ws_size; (void)n_in; (void)in_sizes; (void)out_size;

  // LN1
  k_ln<<<S_PAD, 256, 0, stream>>>(x, ln1w, ln1b, hbuf, S_VALID);

  // QKV GEMM  M=1536 N=3840 K=1280  (64x128/512thr, 720 blocks; B=fp32 weights)
  {
    EpiParams ep = {};
    ep.q = qbuf; ep.k = kbuf; ep.vt = vtb; ep.qb = qb; ep.vb = vb; ep.mvalid = S_VALID;
    ep.wq_ = wq; ep.wk_ = wk; ep.wv_ = wv;
    k_gemm<64, 128, 0><<<dim3(S_PAD / 64, 3 * DMODEL / 128), 512, 0, stream>>>(
        hbuf, 3 * DMODEL, DMODEL, DMODEL, DMODEL, ep);
  }

  // attention: split-KV x2, KVBLK=64  (24 x 20 x 2 = 960 blocks)
  k_attn<<<dim3(S_PAD / 64, NHEAD, 2), 256, 0, stream>>>(
      qbuf, kbuf, vtb, ctxb, opart1, mlbuf);
  k_comb<<<(S_VALID * (DMODEL / 4) + 255) / 256, 256, 0, stream>>>(
      ctxb, opart1, mlbuf);

  // O-proj split-K2 partials  (64x128/512thr, 480 blocks)
  {
    EpiParams ep = {};
    ep.outf = skp; ep.mvalid = S_VALID; ep.w0_ = wo;
    k_gemm<64, 128, 4><<<dim3(S_PAD / 64, DMODEL / 128, 2), 512, 0, stream>>>(
        ctxb, DMODEL, DMODEL / 2, DMODEL, DMODEL, ep);
  }
  k_red<<<(S_VALID * (DMODEL / 4) + 255) / 256, 256, 0, stream>>>(
      skp, ob, x, res2);

  // LN2
  k_ln<<<S_PAD, 256, 0, stream>>>(res2, ln2w, ln2b, h2buf, S_VALID);

  // FC1 + GELU  (64x64/256thr, 1920 blocks)
  {
    EpiParams ep = {};
    ep.bias = fb1; ep.outb = gbuf; ep.mvalid = S_VALID; ep.w0_ = wfc1;
    k_gemm2<64, 64, 2><<<dim3(S_PAD / 64, FFND / 64), 256, 0, stream>>>(
        h2buf, FFND, DMODEL, DMODEL, DMODEL, ep);
  }

  // FC2 split-K2 partials  (64x64/256thr, 960 blocks)  A stride = FFND!
  {
    EpiParams ep = {};
    ep.outf = skp; ep.mvalid = S_VALID; ep.w0_ = wfc2;
    k_gemm2<64, 64, 4><<<dim3(S_PAD / 64, DMODEL / 64, 2), 256, 0, stream>>>(
        gbuf, DMODEL, FFND / 2, FFND, FFND, ep);
  }
  k_red<<<(S_VALID * (DMODEL / 4) + 255) / 256, 256, 0, stream>>>(
      skp, fb2, res2, (float*)d_out);
}

// Round 15
// 187.430 us; speedup vs baseline: 1.6648x; 1.6648x over previous
//
#include <hip/hip_runtime.h>
#include <math.h>

typedef unsigned short u16;
typedef __attribute__((ext_vector_type(8))) short bf16x8;
typedef __attribute__((ext_vector_type(4))) float f32x4;

#define S_VALID 1500
#define S_PAD   1536
#define DMODEL  1280
#define NHEAD   20
#define HDIM    64
#define FFND    5120
#define ZKEYS   768      // keys per KV-split half
#define NSPLIT_TILES 12  // 768 / 64

__device__ __forceinline__ u16 f2bf(float f) {
  union { float f; unsigned u; } v; v.f = f;
  unsigned r = v.u + 0x7fffu + ((v.u >> 16) & 1u);  // RNE
  return (u16)(r >> 16);
}
__device__ __forceinline__ float bf2f(u16 h) {
  union { unsigned u; float f; } v; v.u = ((unsigned)h) << 16; return v.f;
}

template <int N>
__device__ __forceinline__ void wait_vmcnt() {
  if constexpr (N == 8)      asm volatile("s_waitcnt vmcnt(8)"  ::: "memory");
  else if constexpr (N == 6) asm volatile("s_waitcnt vmcnt(6)"  ::: "memory");
  else if constexpr (N == 4) asm volatile("s_waitcnt vmcnt(4)"  ::: "memory");
  else if constexpr (N == 3) asm volatile("s_waitcnt vmcnt(3)"  ::: "memory");
  else if constexpr (N == 2) asm volatile("s_waitcnt vmcnt(2)"  ::: "memory");
  else                       asm volatile("s_waitcnt vmcnt(0)"  ::: "memory");
}

// ---------------- fp32 -> bf16 weight converts (batched) ----------------
__global__ void k_cvt4(const float* __restrict__ s0, const float* __restrict__ s1,
                       const float* __restrict__ s2, const float* __restrict__ s3,
                       u16* __restrict__ d0, u16* __restrict__ d1,
                       u16* __restrict__ d2, u16* __restrict__ d3, int n) {
  const float* in = (blockIdx.y == 0) ? s0 : (blockIdx.y == 1) ? s1 : (blockIdx.y == 2) ? s2 : s3;
  u16* out = (blockIdx.y == 0) ? d0 : (blockIdx.y == 1) ? d1 : (blockIdx.y == 2) ? d2 : d3;
  int i = (blockIdx.x * 256 + threadIdx.x) * 4;
  if (i >= n) return;
  float4 f = *(const float4*)(in + i);
  union { u16 s[4]; uint2 v; } o;
  o.s[0] = f2bf(f.x); o.s[1] = f2bf(f.y); o.s[2] = f2bf(f.z); o.s[3] = f2bf(f.w);
  *(uint2*)(out + i) = o.v;
}
__global__ void k_cvt2(const float* __restrict__ s0, const float* __restrict__ s1,
                       u16* __restrict__ d0, u16* __restrict__ d1, int n) {
  const float* in = (blockIdx.y == 0) ? s0 : s1;
  u16* out = (blockIdx.y == 0) ? d0 : d1;
  int i = (blockIdx.x * 256 + threadIdx.x) * 4;
  if (i >= n) return;
  float4 f = *(const float4*)(in + i);
  union { u16 s[4]; uint2 v; } o;
  o.s[0] = f2bf(f.x); o.s[1] = f2bf(f.y); o.s[2] = f2bf(f.z); o.s[3] = f2bf(f.w);
  *(uint2*)(out + i) = o.v;
}

// ---------------- LayerNorm (fp32 in -> bf16 out, rows padded) ----------------
__global__ __launch_bounds__(256) void k_ln(const float* __restrict__ x,
                                            const float* __restrict__ w,
                                            const float* __restrict__ b,
                                            u16* __restrict__ out, int rows_valid) {
  int r = blockIdx.x;
  int t = threadIdx.x;
  if (r >= rows_valid) {
    for (int i = t; i < DMODEL; i += 256) out[r * DMODEL + i] = 0;
    return;
  }
  const float* xr = x + (size_t)r * DMODEL;
  float vals[5]; float s = 0.f, ss = 0.f;
#pragma unroll
  for (int j = 0; j < 5; ++j) {
    float v = xr[t + j * 256]; vals[j] = v; s += v; ss += v * v;
  }
#pragma unroll
  for (int m = 1; m < 64; m <<= 1) { s += __shfl_xor(s, m); ss += __shfl_xor(ss, m); }
  __shared__ float ps[4], pss[4];
  int lane = t & 63, wv = t >> 6;
  if (lane == 0) { ps[wv] = s; pss[wv] = ss; }
  __syncthreads();
  s = ps[0] + ps[1] + ps[2] + ps[3];
  ss = pss[0] + pss[1] + pss[2] + pss[3];
  float mean = s * (1.f / DMODEL);
  float var = ss * (1.f / DMODEL) - mean * mean;
  float rstd = rsqrtf(var + 1e-5f);
#pragma unroll
  for (int j = 0; j < 5; ++j) {
    int i = t + j * 256;
    out[r * DMODEL + i] = f2bf(w[i] * ((vals[j] - mean) * rstd) + b[i]);
  }
}

// ---------------- GEMM  C[m,n] = sum_k A[m,k]*B[n,k]  (bf16, K-major, BK=64) --
struct EpiParams {
  const float* bias;
  const float* resid;
  float* outf;
  u16* outb;
  u16* q; u16* k; u16* vt;
  const float* qb; const float* vb;
  int mvalid;
};

// NT = threads per block. Wave-uniform LDS base; pre-swizzled global source.
template <int ROWS, int NT>
__device__ __forceinline__ void stage_tile(const u16* __restrict__ g, int ld,
                                           u16* lds, int t) {
  constexpr int ITERS = ROWS * 128 / (NT * 16);   // 128 B per row (BK=64 bf16)
#pragma unroll
  for (int i = 0; i < ITERS; ++i) {
    int off = i * (NT * 16) + t * 16;     // byte offset in tile
    int row = off >> 7;                   // 128B rows
    int sp  = (off >> 4) & 7;             // physical 16B slot
    int s   = sp ^ (row & 7);             // logical slot (pre-swizzled source)
    const u16* gp = g + row * ld + s * 8;
    u16* lp = lds + i * (NT * 8) + ((t >> 6) << 9);   // wave-uniform base (elems)
    __builtin_amdgcn_global_load_lds((const __attribute__((address_space(1))) void*)gp,
                                     (__attribute__((address_space(3))) void*)lp,
                                     16, 0, 0);
  }
}

__device__ __forceinline__ bf16x8 ld_frag(const u16* lds, int row, int kk, int lane) {
  int slot = kk * 4 + (lane >> 4);
  int sp = slot ^ (row & 7);
  return *(const bf16x8*)(lds + row * 64 + sp * 8);
}

// 256-thread, 4-wave (2x2), 64x64 tile (R9-verified config — best for FC1/FC2).
template <int BM, int BN, int EPI>
__global__ __launch_bounds__(256) void k_gemm2(const u16* __restrict__ A,
                                               const u16* __restrict__ B,
                                               int N, int K, int lda, int ldb,
                                               EpiParams ep) {
  constexpr int FM = BM / 32, FN = BN / 32;
  constexpr int LOADS = (BM + BN) / 32;
  __shared__ __align__(128) u16 lds_a[2][BM * 64];
  __shared__ __align__(128) u16 lds_b[2][BN * 64];
  const int t = threadIdx.x, lane = t & 63, wid = t >> 6;
  const int wm = wid >> 1, wn = wid & 1;

  unsigned nwg = gridDim.x * gridDim.y;
  unsigned bid = blockIdx.y * gridDim.x + blockIdx.x;
  unsigned cpx = nwg >> 3;
  bid = (bid & 7u) * cpx + (bid >> 3);
  const int bm0 = (bid % gridDim.x) * BM, bn0 = (bid / gridDim.x) * BN;

  const int l15 = lane & 15, g4 = lane >> 4;

  f32x4 acc[FM][FN] = {};
  const size_t zk = (EPI == 4) ? (size_t)blockIdx.z * K : 0;
  const u16* Ab = A + (size_t)bm0 * lda + zk;
  const u16* Bb = B + (size_t)bn0 * ldb + zk;

  auto stage = [&](int kt, int buf) {
    stage_tile<BM, 256>(Ab + kt * 64, lda, &lds_a[buf][0], t);
    stage_tile<BN, 256>(Bb + kt * 64, ldb, &lds_b[buf][0], t);
  };

  const int NT = K >> 6;
  stage(0, 0);
  int buf = 0;

  for (int kt = 0; kt < NT; ++kt) {
    if (kt + 1 < NT) {
      stage(kt + 1, buf ^ 1);
      wait_vmcnt<LOADS>();
    } else {
      wait_vmcnt<0>();
    }
    __builtin_amdgcn_s_barrier();
    const u16* la = &lds_a[buf][0];
    const u16* lb = &lds_b[buf][0];
#pragma unroll
    for (int kk = 0; kk < 2; ++kk) {
      bf16x8 af[FM], bfr[FN];
#pragma unroll
      for (int i = 0; i < FM; ++i) af[i]  = ld_frag(la, wm * (BM / 2) + i * 16 + l15, kk, lane);
#pragma unroll
      for (int j = 0; j < FN; ++j) bfr[j] = ld_frag(lb, wn * (BN / 2) + j * 16 + l15, kk, lane);
#pragma unroll
      for (int i = 0; i < FM; ++i)
#pragma unroll
        for (int j = 0; j < FN; ++j)
          acc[i][j] = __builtin_amdgcn_mfma_f32_16x16x32_bf16(af[i], bfr[j], acc[i][j], 0, 0, 0);
    }
    __builtin_amdgcn_s_barrier();
    buf ^= 1;
  }

#pragma unroll
  for (int i = 0; i < FM; ++i)
#pragma unroll
    for (int j = 0; j < FN; ++j) {
      int n = bn0 + wn * (BN / 2) + j * 16 + l15;
      int mbase = bm0 + wm * (BM / 2) + i * 16 + g4 * 4;
#pragma unroll
      for (int r = 0; r < 4; ++r) {
        int m = mbase + r;
        float v = acc[i][j][r];
        if constexpr (EPI == 2) {
          float xx = v + ep.bias[n];
          float gg = 0.5f * xx * (1.f + erff(xx * 0.70710678118f));
          ep.outb[(size_t)m * N + n] = f2bf(gg);
        } else if constexpr (EPI == 4) {
          ep.outf[((size_t)blockIdx.z * S_PAD + m) * DMODEL + n] = v;
        }
      }
    }
}

// 512-thread, 8-wave (2M x 4N), 64x128 tile (R12-verified — best for QKV/Oproj).
template <int BM, int BN, int EPI>
__global__ __launch_bounds__(512) void k_gemm(const u16* __restrict__ A,
                                              const u16* __restrict__ B,
                                              int N, int K, int lda, int ldb,
                                              EpiParams ep) {
  constexpr int FM = 2, FN = 2;
  constexpr int LOADS = (BM + BN) * 128 / (512 * 16);
  __shared__ __align__(128) u16 lds_a[2][BM * 64];
  __shared__ __align__(128) u16 lds_b[2][BN * 64];
  const int t = threadIdx.x, lane = t & 63, wid = t >> 6;
  const int wm = wid >> 2, wn = wid & 3;

  unsigned nwg = gridDim.x * gridDim.y;
  unsigned bid = blockIdx.y * gridDim.x + blockIdx.x;
  unsigned cpx = nwg >> 3;
  bid = (bid & 7u) * cpx + (bid >> 3);
  const int bm0 = (bid % gridDim.x) * BM, bn0 = (bid / gridDim.x) * BN;

  const int l15 = lane & 15, g4 = lane >> 4;

  f32x4 acc[FM][FN] = {};
  const size_t zk = (EPI == 4) ? (size_t)blockIdx.z * K : 0;
  const u16* Ab = A + (size_t)bm0 * lda + zk;
  const u16* Bb = B + (size_t)bn0 * ldb + zk;

  auto stage = [&](int kt, int buf) {
    stage_tile<BM, 512>(Ab + kt * 64, lda, &lds_a[buf][0], t);
    stage_tile<BN, 512>(Bb + kt * 64, ldb, &lds_b[buf][0], t);
  };

  const int NT = K >> 6;
  stage(0, 0);
  int buf = 0;

  for (int kt = 0; kt < NT; ++kt) {
    if (kt + 1 < NT) {
      stage(kt + 1, buf ^ 1);
      wait_vmcnt<LOADS>();
    } else {
      wait_vmcnt<0>();
    }
    __builtin_amdgcn_s_barrier();
    const u16* la = &lds_a[buf][0];
    const u16* lb = &lds_b[buf][0];
#pragma unroll
    for (int kk = 0; kk < 2; ++kk) {
      bf16x8 af[FM], bfr[FN];
#pragma unroll
      for (int i = 0; i < FM; ++i) af[i]  = ld_frag(la, wm * (BM / 2) + i * 16 + l15, kk, lane);
#pragma unroll
      for (int j = 0; j < FN; ++j) bfr[j] = ld_frag(lb, wn * (BN / 4) + j * 16 + l15, kk, lane);
#pragma unroll
      for (int i = 0; i < FM; ++i)
#pragma unroll
        for (int j = 0; j < FN; ++j)
          acc[i][j] = __builtin_amdgcn_mfma_f32_16x16x32_bf16(af[i], bfr[j], acc[i][j], 0, 0, 0);
    }
    __builtin_amdgcn_s_barrier();
    buf ^= 1;
  }

#pragma unroll
  for (int i = 0; i < FM; ++i)
#pragma unroll
    for (int j = 0; j < FN; ++j) {
      int n = bn0 + wn * (BN / 4) + j * 16 + l15;
      int mbase = bm0 + wm * (BM / 2) + i * 16 + g4 * 4;
      if constexpr (EPI == 0) {
        if (n >= 2 * DMODEL) {
          int nn = n - 2 * DMODEL;
          union { u16 s[4]; uint2 v2; } pk;
#pragma unroll
          for (int r = 0; r < 4; ++r) {
            int m = mbase + r;
            float val = (m < ep.mvalid) ? (acc[i][j][r] + ep.vb[nn]) : 0.f;
            pk.s[r] = f2bf(val);
          }
          *(uint2*)(ep.vt + (size_t)nn * S_PAD + mbase) = pk.v2;
        } else {
#pragma unroll
          for (int r = 0; r < 4; ++r) {
            int m = mbase + r;
            float v = acc[i][j][r];
            if (n < DMODEL) {
              float val = (m < ep.mvalid) ? (v + ep.qb[n]) * 0.125f : 0.f;
              ep.q[m * DMODEL + n] = f2bf(val);
            } else {
              int nn = n - DMODEL;
              ep.k[m * DMODEL + nn] = f2bf(m < ep.mvalid ? v : 0.f);
            }
          }
        }
      } else {
#pragma unroll
        for (int r = 0; r < 4; ++r) {
          int m = mbase + r;
          float v = acc[i][j][r];
          if constexpr (EPI == 4) {
            ep.outf[((size_t)blockIdx.z * S_PAD + m) * DMODEL + n] = v;
          }
        }
      }
    }
}

// ---------------- split-K reducer: out = p0 + p1 + bias + resid --------------
__global__ __launch_bounds__(256) void k_red(const float* __restrict__ p,
                                             const float* __restrict__ bias,
                                             const float* __restrict__ resid,
                                             float* __restrict__ out) {
  int idx = blockIdx.x * 256 + threadIdx.x;
  if (idx >= S_VALID * (DMODEL / 4)) return;
  int m = idx / (DMODEL / 4), n4 = (idx % (DMODEL / 4)) * 4;
  float4 a  = *(const float4*)(p + (size_t)m * DMODEL + n4);
  float4 b  = *(const float4*)(p + ((size_t)S_PAD + m) * DMODEL + n4);
  float4 rs = *(const float4*)(resid + (size_t)m * DMODEL + n4);
  float4 bb = *(const float4*)(bias + n4);
  float4 o;
  o.x = a.x + b.x + rs.x + bb.x;
  o.y = a.y + b.y + rs.y + bb.y;
  o.z = a.z + b.z + rs.z + bb.z;
  o.w = a.w + b.w + rs.w + bb.w;
  *(float4*)(out + (size_t)m * DMODEL + n4) = o;
}

// ---- flash attention, split-KV x2, KVBLK=64 (two verified 32-key subtiles) --
__global__ __launch_bounds__(256) void k_attn(const u16* __restrict__ q,
                                              const u16* __restrict__ k,
                                              const u16* __restrict__ vt,
                                              u16* __restrict__ o0,
                                              u16* __restrict__ o1,
                                              float2* __restrict__ ml) {
  __shared__ __align__(128) u16 kls[2][2][2048];
  __shared__ __align__(128) u16 vls[2][2][2048];
  const int t = threadIdx.x;
  const int lane = t & 63, wid = t >> 6;
  const int h = blockIdx.y, z = blockIdx.z;
  const int zb = z * ZKEYS;
  const int qbase = blockIdx.x * 64 + wid * 16;
  const int l15 = lane & 15, g = lane >> 4;

  const int srow = t >> 3;
  const int psl  = t & 7;
  const int slog = psl ^ (srow & 7);
  const int kperm = 8 * ((srow & 15) >> 2) + (srow & 3) + 4 * (srow >> 4);
  const int vd    = 2 * srow + (slog >> 2);
  const int vkoff = (slog & 3) * 8;
  const u16* kbasep = k + (size_t)kperm * DMODEL + h * HDIM + slog * 8;
  const u16* vbasep = vt + (size_t)(h * HDIM + vd) * S_PAD + vkoff;
  const int wbase = (t >> 6) << 9;

  bf16x8 qf[2];
#pragma unroll
  for (int half = 0; half < 2; ++half)
    qf[half] = *(const bf16x8*)(q + (qbase + l15) * DMODEL + h * HDIM + half * 32 + g * 8);

  auto stage = [&](int tt, int buf) {
#pragma unroll
    for (int u = 0; u < 2; ++u) {
      int keyoff = zb + tt * 64 + u * 32;
      __builtin_amdgcn_global_load_lds(
          (const __attribute__((address_space(1))) void*)(kbasep + (size_t)keyoff * DMODEL),
          (__attribute__((address_space(3))) void*)(&kls[buf][u][0] + wbase), 16, 0, 0);
      __builtin_amdgcn_global_load_lds(
          (const __attribute__((address_space(1))) void*)(vbasep + keyoff),
          (__attribute__((address_space(3))) void*)(&vls[buf][u][0] + wbase), 16, 0, 0);
    }
  };

  stage(0, 0);
  int buf = 0;

  float Mx = -1e30f, L = 0.f;
  f32x4 c[4] = {};

  for (int tt = 0; tt < NSPLIT_TILES; ++tt) {
    if (tt + 1 < NSPLIT_TILES) {
      stage(tt + 1, buf ^ 1);
      wait_vmcnt<4>();
    } else {
      wait_vmcnt<0>();
    }
    __builtin_amdgcn_s_barrier();

    f32x4 sc[2][2];
#pragma unroll
    for (int u = 0; u < 2; ++u)
#pragma unroll
      for (int s = 0; s < 2; ++s) {
        int row = 16 * s + l15;
        const u16* kb = &kls[buf][u][0];
        bf16x8 ka0 = *(const bf16x8*)(kb + row * 64 + ((g)     ^ (row & 7)) * 8);
        bf16x8 ka1 = *(const bf16x8*)(kb + row * 64 + ((4 + g) ^ (row & 7)) * 8);
        f32x4 zz = {};
        zz = __builtin_amdgcn_mfma_f32_16x16x32_bf16(ka0, qf[0], zz, 0, 0, 0);
        zz = __builtin_amdgcn_mfma_f32_16x16x32_bf16(ka1, qf[1], zz, 0, 0, 0);
        sc[u][s] = zz;
      }
    float pm = -1e30f;
#pragma unroll
    for (int u = 0; u < 2; ++u)
#pragma unroll
      for (int s = 0; s < 2; ++s)
#pragma unroll
        for (int r = 0; r < 4; ++r) {
          int kg = zb + tt * 64 + u * 32 + 8 * g + 4 * s + r;
          float v = (kg < S_VALID) ? sc[u][s][r] : -1e30f;
          sc[u][s][r] = v;
          pm = fmaxf(pm, v);
        }
    pm = fmaxf(pm, __shfl_xor(pm, 16));
    pm = fmaxf(pm, __shfl_xor(pm, 32));
    float Mn = fmaxf(Mx, pm);
    float fac = __expf(Mx - Mn);
    float p[2][8]; float rs = 0.f;
#pragma unroll
    for (int u = 0; u < 2; ++u)
#pragma unroll
      for (int s = 0; s < 2; ++s)
#pragma unroll
        for (int r = 0; r < 4; ++r) {
          float e = __expf(sc[u][s][r] - Mn);
          p[u][4 * s + r] = e; rs += e;
        }
    rs += __shfl_xor(rs, 16);
    rs += __shfl_xor(rs, 32);
    L = L * fac + rs; Mx = Mn;

    float facr[4];
#pragma unroll
    for (int r = 0; r < 4; ++r) facr[r] = __shfl(fac, g * 20 + r);
#pragma unroll
    for (int ch = 0; ch < 4; ++ch)
#pragma unroll
      for (int r = 0; r < 4; ++r) c[ch][r] *= facr[r];

    bf16x8 pa[2];
#pragma unroll
    for (int u = 0; u < 2; ++u)
#pragma unroll
      for (int j = 0; j < 8; ++j) pa[u][j] = (short)f2bf(p[u][j]);
#pragma unroll
    for (int ch = 0; ch < 4; ++ch) {
      int R = 8 * ch + (l15 >> 1);
      int sl = (l15 & 1) * 4 + g;
#pragma unroll
      for (int u = 0; u < 2; ++u) {
        bf16x8 vbf = *(const bf16x8*)(&vls[buf][u][0] + R * 64 + (sl ^ (R & 7)) * 8);
        c[ch] = __builtin_amdgcn_mfma_f32_16x16x32_bf16(pa[u], vbf, c[ch], 0, 0, 0);
      }
    }
    __builtin_amdgcn_s_barrier();
    buf ^= 1;
  }

  u16* op = z ? o1 : o0;
  if (g == 0) ml[(size_t)(z * NHEAD + h) * S_PAD + qbase + l15] = make_float2(Mx, L);
#pragma unroll
  for (int ch = 0; ch < 4; ++ch)
#pragma unroll
    for (int r = 0; r < 4; ++r) {
      int m = qbase + g * 4 + r;
      op[(size_t)m * DMODEL + h * HDIM + ch * 16 + l15] = f2bf(c[ch][r]);
    }
}

// ---------------- combine the two KV halves (exact fp32 LSE merge) -----------
__global__ __launch_bounds__(256) void k_comb(u16* __restrict__ o0,
                                              const u16* __restrict__ o1,
                                              const float2* __restrict__ ml) {
  int idx = blockIdx.x * 256 + threadIdx.x;
  if (idx >= S_VALID * (DMODEL / 4)) return;
  int m = idx / (DMODEL / 4);
  int d = (idx % (DMODEL / 4)) * 4;
  int h = d >> 6;
  float2 a = ml[(size_t)h * S_PAD + m];
  float2 b = ml[(size_t)(NHEAD + h) * S_PAD + m];
  float M = fmaxf(a.x, b.x);
  float w0 = __expf(a.x - M), w1 = __expf(b.x - M);
  float inv = 1.f / (w0 * a.y + w1 * b.y);
  w0 *= inv; w1 *= inv;
  union { u16 s[4]; uint2 v; } A, B, O;
  A.v = *(const uint2*)(o0 + (size_t)m * DMODEL + d);
  B.v = *(const uint2*)(o1 + (size_t)m * DMODEL + d);
#pragma unroll
  for (int j = 0; j < 4; ++j)
    O.s[j] = f2bf(w0 * bf2f(A.s[j]) + w1 * bf2f(B.s[j]));
  *(uint2*)(o0 + (size_t)m * DMODEL + d) = O.v;
}

// ----------------------------------------------------------------------------
extern "C" void kernel_launch(void* const* d_in, const int* in_sizes, int n_in,
                              void* d_out, int out_size, void* d_ws, size_t ws_size,
                              hipStream_t stream) {
  const float* x    = (const float*)d_in[0];
  const float* ln1w = (const float*)d_in[1];
  const float* ln1b = (const float*)d_in[2];
  const float* ln2w = (const float*)d_in[3];
  const float* ln2b = (const float*)d_in[4];
  const float* wq   = (const float*)d_in[5];
  const float* qb   = (const float*)d_in[6];
  const float* wk   = (const float*)d_in[7];
  const float* wv   = (const float*)d_in[8];
  const float* vb   = (const float*)d_in[9];
  const float* wo   = (const float*)d_in[10];
  const float* ob   = (const float*)d_in[11];
  const float* wfc1 = (const float*)d_in[12];
  const float* fb1  = (const float*)d_in[13];
  const float* wfc2 = (const float*)d_in[14];
  const float* fb2  = (const float*)d_in[15];

  char* ws = (char*)d_ws;
  size_t off = 0;
  auto alloc = [&](size_t bytes) {
    void* p = ws + off; off += (bytes + 255) & ~(size_t)255; return p;
  };
  u16*   w_qkv = (u16*)alloc((size_t)3 * DMODEL * DMODEL * 2);
  u16*   w_o   = (u16*)alloc((size_t)DMODEL * DMODEL * 2);
  u16*   w_f1  = (u16*)alloc((size_t)FFND * DMODEL * 2);
  u16*   w_f2  = (u16*)alloc((size_t)DMODEL * FFND * 2);
  u16*   hbuf  = (u16*)alloc((size_t)S_PAD * DMODEL * 2);
  u16*   qbuf  = (u16*)alloc((size_t)S_PAD * DMODEL * 2);
  u16*   kbuf  = (u16*)alloc((size_t)S_PAD * DMODEL * 2);
  u16*   vtb   = (u16*)alloc((size_t)DMODEL * S_PAD * 2);
  u16*   ctxb  = (u16*)alloc((size_t)S_PAD * DMODEL * 2);
  float* res2  = (float*)alloc((size_t)S_PAD * DMODEL * 4);
  u16*   h2buf = (u16*)alloc((size_t)S_PAD * DMODEL * 2);
  u16*   gbuf  = (u16*)alloc((size_t)S_PAD * FFND * 2);
  float* skp   = (float*)hbuf;
  u16*    opart1 = (u16*)res2;
  float2* mlbuf  = (float2*)((char*)res2 + (size_t)S_PAD * DMODEL * 2);
  (void)ws_size; (void)n_in; (void)in_sizes; (void)out_size;

  const int nDD = DMODEL * DMODEL;
  const int nF  = FFND * DMODEL;
  k_cvt4<<<dim3(nDD / 1024, 4), 256, 0, stream>>>(
      wq, wk, wv, wo, w_qkv, w_qkv + (size_t)nDD, w_qkv + (size_t)2 * nDD, w_o, nDD);
  k_cvt2<<<dim3(nF / 1024, 2), 256, 0, stream>>>(wfc1, wfc2, w_f1, w_f2, nF);

  // LN1
  k_ln<<<S_PAD, 256, 0, stream>>>(x, ln1w, ln1b, hbuf, S_VALID);

  // QKV GEMM  M=1536 N=3840 K=1280  (64x128/512thr, 720 blocks — R12 best)
  {
    EpiParams ep = {};
    ep.q = qbuf; ep.k = kbuf; ep.vt = vtb; ep.qb = qb; ep.vb = vb; ep.mvalid = S_VALID;
    k_gemm<64, 128, 0><<<dim3(S_PAD / 64, 3 * DMODEL / 128), 512, 0, stream>>>(
        hbuf, w_qkv, 3 * DMODEL, DMODEL, DMODEL, DMODEL, ep);
  }

  // attention: split-KV x2, KVBLK=64  (24 x 20 x 2 = 960 blocks)
  k_attn<<<dim3(S_PAD / 64, NHEAD, 2), 256, 0, stream>>>(
      qbuf, kbuf, vtb, ctxb, opart1, mlbuf);
  k_comb<<<(S_VALID * (DMODEL / 4) + 255) / 256, 256, 0, stream>>>(
      ctxb, opart1, mlbuf);

  // O-proj split-K2 partials  (64x128/512thr, 480 blocks — R12 best)
  {
    EpiParams ep = {};
    ep.outf = skp; ep.mvalid = S_VALID;
    k_gemm<64, 128, 4><<<dim3(S_PAD / 64, DMODEL / 128, 2), 512, 0, stream>>>(
        ctxb, w_o, DMODEL, DMODEL / 2, DMODEL, DMODEL, ep);
  }
  k_red<<<(S_VALID * (DMODEL / 4) + 255) / 256, 256, 0, stream>>>(
      skp, ob, x, res2);

  // LN2
  k_ln<<<S_PAD, 256, 0, stream>>>(res2, ln2w, ln2b, h2buf, S_VALID);

  // FC1 + GELU  (64x64/256thr, 1920 blocks — R9 best)
  {
    EpiParams ep = {};
    ep.bias = fb1; ep.outb = gbuf; ep.mvalid = S_VALID;
    k_gemm2<64, 64, 2><<<dim3(S_PAD / 64, FFND / 64), 256, 0, stream>>>(
        h2buf, w_f1, FFND, DMODEL, DMODEL, DMODEL, ep);
  }

  // FC2 split-K2 partials  (64x64/256thr, 960 blocks — R9 best)  lda = FFND!
  {
    EpiParams ep = {};
    ep.outf = skp; ep.mvalid = S_VALID;
    k_gemm2<64, 64, 4><<<dim3(S_PAD / 64, DMODEL / 64, 2), 256, 0, stream>>>(
        gbuf, w_f2, DMODEL, FFND / 2, FFND, FFND, ep);
  }
  k_red<<<(S_VALID * (DMODEL / 4) + 255) / 256, 256, 0, stream>>>(
      skp, fb2, res2, (float*)d_out);
}

// Round 16
// 184.617 us; speedup vs baseline: 1.6902x; 1.0152x over previous
//
#include <hip/hip_runtime.h>
#include <math.h>

typedef unsigned short u16;
typedef __attribute__((ext_vector_type(8))) short bf16x8;
typedef __attribute__((ext_vector_type(4))) float f32x4;

#define S_VALID 1500
#define S_PAD   1536
#define DMODEL  1280
#define NHEAD   20
#define HDIM    64
#define FFND    5120
#define ZKEYS   768      // keys per KV-split half
#define NSPLIT_TILES 12  // 768 / 64

__device__ __forceinline__ u16 f2bf(float f) {
  union { float f; unsigned u; } v; v.f = f;
  unsigned r = v.u + 0x7fffu + ((v.u >> 16) & 1u);  // RNE
  return (u16)(r >> 16);
}
__device__ __forceinline__ float bf2f(u16 h) {
  union { unsigned u; float f; } v; v.u = ((unsigned)h) << 16; return v.f;
}

template <int N>
__device__ __forceinline__ void wait_vmcnt() {
  if constexpr (N == 8)      asm volatile("s_waitcnt vmcnt(8)"  ::: "memory");
  else if constexpr (N == 6) asm volatile("s_waitcnt vmcnt(6)"  ::: "memory");
  else if constexpr (N == 4) asm volatile("s_waitcnt vmcnt(4)"  ::: "memory");
  else if constexpr (N == 3) asm volatile("s_waitcnt vmcnt(3)"  ::: "memory");
  else if constexpr (N == 2) asm volatile("s_waitcnt vmcnt(2)"  ::: "memory");
  else                       asm volatile("s_waitcnt vmcnt(0)"  ::: "memory");
}

// ---------------- fp32 -> bf16 weight converts (batched) ----------------
__global__ void k_cvt4(const float* __restrict__ s0, const float* __restrict__ s1,
                       const float* __restrict__ s2, const float* __restrict__ s3,
                       u16* __restrict__ d0, u16* __restrict__ d1,
                       u16* __restrict__ d2, u16* __restrict__ d3, int n) {
  const float* in = (blockIdx.y == 0) ? s0 : (blockIdx.y == 1) ? s1 : (blockIdx.y == 2) ? s2 : s3;
  u16* out = (blockIdx.y == 0) ? d0 : (blockIdx.y == 1) ? d1 : (blockIdx.y == 2) ? d2 : d3;
  int i = (blockIdx.x * 256 + threadIdx.x) * 4;
  if (i >= n) return;
  float4 f = *(const float4*)(in + i);
  union { u16 s[4]; uint2 v; } o;
  o.s[0] = f2bf(f.x); o.s[1] = f2bf(f.y); o.s[2] = f2bf(f.z); o.s[3] = f2bf(f.w);
  *(uint2*)(out + i) = o.v;
}
__global__ void k_cvt2(const float* __restrict__ s0, const float* __restrict__ s1,
                       u16* __restrict__ d0, u16* __restrict__ d1, int n) {
  const float* in = (blockIdx.y == 0) ? s0 : s1;
  u16* out = (blockIdx.y == 0) ? d0 : d1;
  int i = (blockIdx.x * 256 + threadIdx.x) * 4;
  if (i >= n) return;
  float4 f = *(const float4*)(in + i);
  union { u16 s[4]; uint2 v; } o;
  o.s[0] = f2bf(f.x); o.s[1] = f2bf(f.y); o.s[2] = f2bf(f.z); o.s[3] = f2bf(f.w);
  *(uint2*)(out + i) = o.v;
}

// ---------------- LayerNorm (fp32 in -> bf16 out, rows padded) ----------------
__global__ __launch_bounds__(256) void k_ln(const float* __restrict__ x,
                                            const float* __restrict__ w,
                                            const float* __restrict__ b,
                                            u16* __restrict__ out, int rows_valid) {
  int r = blockIdx.x;
  int t = threadIdx.x;
  if (r >= rows_valid) {
    for (int i = t; i < DMODEL; i += 256) out[r * DMODEL + i] = 0;
    return;
  }
  const float* xr = x + (size_t)r * DMODEL;
  float vals[5]; float s = 0.f, ss = 0.f;
#pragma unroll
  for (int j = 0; j < 5; ++j) {
    float v = xr[t + j * 256]; vals[j] = v; s += v; ss += v * v;
  }
#pragma unroll
  for (int m = 1; m < 64; m <<= 1) { s += __shfl_xor(s, m); ss += __shfl_xor(ss, m); }
  __shared__ float ps[4], pss[4];
  int lane = t & 63, wv = t >> 6;
  if (lane == 0) { ps[wv] = s; pss[wv] = ss; }
  __syncthreads();
  s = ps[0] + ps[1] + ps[2] + ps[3];
  ss = pss[0] + pss[1] + pss[2] + pss[3];
  float mean = s * (1.f / DMODEL);
  float var = ss * (1.f / DMODEL) - mean * mean;
  float rstd = rsqrtf(var + 1e-5f);
#pragma unroll
  for (int j = 0; j < 5; ++j) {
    int i = t + j * 256;
    out[r * DMODEL + i] = f2bf(w[i] * ((vals[j] - mean) * rstd) + b[i]);
  }
}

// ---------------- GEMM  C[m,n] = sum_k A[m,k]*B[n,k]  (bf16, K-major, BK=64) --
struct EpiParams {
  const float* bias;
  const float* resid;
  float* outf;
  u16* outb;
  u16* q; u16* k; u16* vt;
  const float* qb; const float* vb;
  int mvalid;
};

// NT = threads per block. Wave-uniform LDS base; pre-swizzled global source.
template <int ROWS, int NT>
__device__ __forceinline__ void stage_tile(const u16* __restrict__ g, int ld,
                                           u16* lds, int t) {
  constexpr int ITERS = ROWS * 128 / (NT * 16);   // 128 B per row (BK=64 bf16)
#pragma unroll
  for (int i = 0; i < ITERS; ++i) {
    int off = i * (NT * 16) + t * 16;     // byte offset in tile
    int row = off >> 7;                   // 128B rows
    int sp  = (off >> 4) & 7;             // physical 16B slot
    int s   = sp ^ (row & 7);             // logical slot (pre-swizzled source)
    const u16* gp = g + row * ld + s * 8;
    u16* lp = lds + i * (NT * 8) + ((t >> 6) << 9);   // wave-uniform base (elems)
    __builtin_amdgcn_global_load_lds((const __attribute__((address_space(1))) void*)gp,
                                     (__attribute__((address_space(3))) void*)lp,
                                     16, 0, 0);
  }
}

__device__ __forceinline__ bf16x8 ld_frag(const u16* lds, int row, int kk, int lane) {
  int slot = kk * 4 + (lane >> 4);
  int sp = slot ^ (row & 7);
  return *(const bf16x8*)(lds + row * 64 + sp * 8);
}

// 256-thread, 4-wave (2x2), 64x64 tile (R9-verified).
template <int BM, int BN, int EPI>
__global__ __launch_bounds__(256) void k_gemm2(const u16* __restrict__ A,
                                               const u16* __restrict__ B,
                                               int N, int K, int lda, int ldb,
                                               EpiParams ep) {
  constexpr int FM = BM / 32, FN = BN / 32;
  constexpr int LOADS = (BM + BN) / 32;
  __shared__ __align__(128) u16 lds_a[2][BM * 64];
  __shared__ __align__(128) u16 lds_b[2][BN * 64];
  const int t = threadIdx.x, lane = t & 63, wid = t >> 6;
  const int wm = wid >> 1, wn = wid & 1;

  unsigned nwg = gridDim.x * gridDim.y;
  unsigned bid = blockIdx.y * gridDim.x + blockIdx.x;
  unsigned cpx = nwg >> 3;
  bid = (bid & 7u) * cpx + (bid >> 3);
  const int bm0 = (bid % gridDim.x) * BM, bn0 = (bid / gridDim.x) * BN;

  const int l15 = lane & 15, g4 = lane >> 4;

  f32x4 acc[FM][FN] = {};
  const size_t zk = (EPI == 4) ? (size_t)blockIdx.z * K : 0;
  const u16* Ab = A + (size_t)bm0 * lda + zk;
  const u16* Bb = B + (size_t)bn0 * ldb + zk;

  auto stage = [&](int kt, int buf) {
    stage_tile<BM, 256>(Ab + kt * 64, lda, &lds_a[buf][0], t);
    stage_tile<BN, 256>(Bb + kt * 64, ldb, &lds_b[buf][0], t);
  };

  const int NT = K >> 6;
  stage(0, 0);
  int buf = 0;

  for (int kt = 0; kt < NT; ++kt) {
    if (kt + 1 < NT) {
      stage(kt + 1, buf ^ 1);
      wait_vmcnt<LOADS>();
    } else {
      wait_vmcnt<0>();
    }
    __builtin_amdgcn_s_barrier();
    const u16* la = &lds_a[buf][0];
    const u16* lb = &lds_b[buf][0];
#pragma unroll
    for (int kk = 0; kk < 2; ++kk) {
      bf16x8 af[FM], bfr[FN];
#pragma unroll
      for (int i = 0; i < FM; ++i) af[i]  = ld_frag(la, wm * (BM / 2) + i * 16 + l15, kk, lane);
#pragma unroll
      for (int j = 0; j < FN; ++j) bfr[j] = ld_frag(lb, wn * (BN / 2) + j * 16 + l15, kk, lane);
#pragma unroll
      for (int i = 0; i < FM; ++i)
#pragma unroll
        for (int j = 0; j < FN; ++j)
          acc[i][j] = __builtin_amdgcn_mfma_f32_16x16x32_bf16(af[i], bfr[j], acc[i][j], 0, 0, 0);
    }
    __builtin_amdgcn_s_barrier();
    buf ^= 1;
  }

#pragma unroll
  for (int i = 0; i < FM; ++i)
#pragma unroll
    for (int j = 0; j < FN; ++j) {
      int n = bn0 + wn * (BN / 2) + j * 16 + l15;
      int mbase = bm0 + wm * (BM / 2) + i * 16 + g4 * 4;
#pragma unroll
      for (int r = 0; r < 4; ++r) {
        int m = mbase + r;
        float v = acc[i][j][r];
        if constexpr (EPI == 2) {
          float xx = v + ep.bias[n];
          float gg = 0.5f * xx * (1.f + erff(xx * 0.70710678118f));
          ep.outb[(size_t)m * N + n] = f2bf(gg);
        } else if constexpr (EPI == 4) {
          ep.outf[((size_t)blockIdx.z * S_PAD + m) * DMODEL + n] = v;
        }
      }
    }
}

// 512-thread, 8-wave (2M x 4N), 64x128 tile (R12-verified — QKV / O-proj).
template <int BM, int BN, int EPI>
__global__ __launch_bounds__(512) void k_gemm(const u16* __restrict__ A,
                                              const u16* __restrict__ B,
                                              int N, int K, int lda, int ldb,
                                              EpiParams ep) {
  constexpr int FM = 2, FN = 2;
  constexpr int LOADS = (BM + BN) * 128 / (512 * 16);
  __shared__ __align__(128) u16 lds_a[2][BM * 64];
  __shared__ __align__(128) u16 lds_b[2][BN * 64];
  const int t = threadIdx.x, lane = t & 63, wid = t >> 6;
  const int wm = wid >> 2, wn = wid & 3;

  unsigned nwg = gridDim.x * gridDim.y;
  unsigned bid = blockIdx.y * gridDim.x + blockIdx.x;
  unsigned cpx = nwg >> 3;
  bid = (bid & 7u) * cpx + (bid >> 3);
  const int bm0 = (bid % gridDim.x) * BM, bn0 = (bid / gridDim.x) * BN;

  const int l15 = lane & 15, g4 = lane >> 4;

  f32x4 acc[FM][FN] = {};
  const size_t zk = (EPI == 4) ? (size_t)blockIdx.z * K : 0;
  const u16* Ab = A + (size_t)bm0 * lda + zk;
  const u16* Bb = B + (size_t)bn0 * ldb + zk;

  auto stage = [&](int kt, int buf) {
    stage_tile<BM, 512>(Ab + kt * 64, lda, &lds_a[buf][0], t);
    stage_tile<BN, 512>(Bb + kt * 64, ldb, &lds_b[buf][0], t);
  };

  const int NT = K >> 6;
  stage(0, 0);
  int buf = 0;

  for (int kt = 0; kt < NT; ++kt) {
    if (kt + 1 < NT) {
      stage(kt + 1, buf ^ 1);
      wait_vmcnt<LOADS>();
    } else {
      wait_vmcnt<0>();
    }
    __builtin_amdgcn_s_barrier();
    const u16* la = &lds_a[buf][0];
    const u16* lb = &lds_b[buf][0];
#pragma unroll
    for (int kk = 0; kk < 2; ++kk) {
      bf16x8 af[FM], bfr[FN];
#pragma unroll
      for (int i = 0; i < FM; ++i) af[i]  = ld_frag(la, wm * (BM / 2) + i * 16 + l15, kk, lane);
#pragma unroll
      for (int j = 0; j < FN; ++j) bfr[j] = ld_frag(lb, wn * (BN / 4) + j * 16 + l15, kk, lane);
#pragma unroll
      for (int i = 0; i < FM; ++i)
#pragma unroll
        for (int j = 0; j < FN; ++j)
          acc[i][j] = __builtin_amdgcn_mfma_f32_16x16x32_bf16(af[i], bfr[j], acc[i][j], 0, 0, 0);
    }
    __builtin_amdgcn_s_barrier();
    buf ^= 1;
  }

#pragma unroll
  for (int i = 0; i < FM; ++i)
#pragma unroll
    for (int j = 0; j < FN; ++j) {
      int n = bn0 + wn * (BN / 4) + j * 16 + l15;
      int mbase = bm0 + wm * (BM / 2) + i * 16 + g4 * 4;
      if constexpr (EPI == 0) {
        if (n >= 2 * DMODEL) {
          int nn = n - 2 * DMODEL;
          union { u16 s[4]; uint2 v2; } pk;
#pragma unroll
          for (int r = 0; r < 4; ++r) {
            int m = mbase + r;
            float val = (m < ep.mvalid) ? (acc[i][j][r] + ep.vb[nn]) : 0.f;
            pk.s[r] = f2bf(val);
          }
          *(uint2*)(ep.vt + (size_t)nn * S_PAD + mbase) = pk.v2;
        } else {
#pragma unroll
          for (int r = 0; r < 4; ++r) {
            int m = mbase + r;
            float v = acc[i][j][r];
            if (n < DMODEL) {
              float val = (m < ep.mvalid) ? (v + ep.qb[n]) * 0.125f : 0.f;
              ep.q[m * DMODEL + n] = f2bf(val);
            } else {
              int nn = n - DMODEL;
              ep.k[m * DMODEL + nn] = f2bf(m < ep.mvalid ? v : 0.f);
            }
          }
        }
      } else {
#pragma unroll
        for (int r = 0; r < 4; ++r) {
          int m = mbase + r;
          float v = acc[i][j][r];
          if constexpr (EPI == 4) {
            ep.outf[((size_t)blockIdx.z * S_PAD + m) * DMODEL + n] = v;
          }
        }
      }
    }
}

// 512-thread, 8-wave (2M x 4N), 128x128 tile — NEW cell for FC1/FC2.
// Per wave: 64x32 output (FM=4, FN=2). LDS 64KB -> 2 blocks/CU (16 waves/CU).
// Staged bytes/FLOP = 2/128 — half of the 64x64 config.
template <int BM, int BN, int EPI>
__global__ __launch_bounds__(512) void k_gemm3(const u16* __restrict__ A,
                                               const u16* __restrict__ B,
                                               int N, int K, int lda, int ldb,
                                               EpiParams ep) {
  constexpr int FM = 4, FN = 2;
  constexpr int LOADS = (BM + BN) * 128 / (512 * 16);   // = 4
  __shared__ __align__(128) u16 lds_a[2][BM * 64];
  __shared__ __align__(128) u16 lds_b[2][BN * 64];
  const int t = threadIdx.x, lane = t & 63, wid = t >> 6;
  const int wm = wid >> 2, wn = wid & 3;                // 2M x 4N wave grid

  unsigned nwg = gridDim.x * gridDim.y;
  unsigned bid = blockIdx.y * gridDim.x + blockIdx.x;
  unsigned cpx = nwg >> 3;
  bid = (bid & 7u) * cpx + (bid >> 3);
  const int bm0 = (bid % gridDim.x) * BM, bn0 = (bid / gridDim.x) * BN;

  const int l15 = lane & 15, g4 = lane >> 4;

  f32x4 acc[FM][FN] = {};
  const size_t zk = (EPI == 4) ? (size_t)blockIdx.z * K : 0;
  const u16* Ab = A + (size_t)bm0 * lda + zk;
  const u16* Bb = B + (size_t)bn0 * ldb + zk;

  auto stage = [&](int kt, int buf) {
    stage_tile<BM, 512>(Ab + kt * 64, lda, &lds_a[buf][0], t);
    stage_tile<BN, 512>(Bb + kt * 64, ldb, &lds_b[buf][0], t);
  };

  const int NT = K >> 6;
  stage(0, 0);
  int buf = 0;

  for (int kt = 0; kt < NT; ++kt) {
    if (kt + 1 < NT) {
      stage(kt + 1, buf ^ 1);
      wait_vmcnt<LOADS>();
    } else {
      wait_vmcnt<0>();
    }
    __builtin_amdgcn_s_barrier();
    const u16* la = &lds_a[buf][0];
    const u16* lb = &lds_b[buf][0];
#pragma unroll
    for (int kk = 0; kk < 2; ++kk) {
      bf16x8 af[FM], bfr[FN];
#pragma unroll
      for (int i = 0; i < FM; ++i) af[i]  = ld_frag(la, wm * 64 + i * 16 + l15, kk, lane);
#pragma unroll
      for (int j = 0; j < FN; ++j) bfr[j] = ld_frag(lb, wn * 32 + j * 16 + l15, kk, lane);
#pragma unroll
      for (int i = 0; i < FM; ++i)
#pragma unroll
        for (int j = 0; j < FN; ++j)
          acc[i][j] = __builtin_amdgcn_mfma_f32_16x16x32_bf16(af[i], bfr[j], acc[i][j], 0, 0, 0);
    }
    __builtin_amdgcn_s_barrier();
    buf ^= 1;
  }

#pragma unroll
  for (int i = 0; i < FM; ++i)
#pragma unroll
    for (int j = 0; j < FN; ++j) {
      int n = bn0 + wn * 32 + j * 16 + l15;
      int mbase = bm0 + wm * 64 + i * 16 + g4 * 4;
#pragma unroll
      for (int r = 0; r < 4; ++r) {
        int m = mbase + r;
        float v = acc[i][j][r];
        if constexpr (EPI == 2) {
          float xx = v + ep.bias[n];
          float gg = 0.5f * xx * (1.f + erff(xx * 0.70710678118f));
          ep.outb[(size_t)m * N + n] = f2bf(gg);
        } else if constexpr (EPI == 4) {
          ep.outf[((size_t)blockIdx.z * S_PAD + m) * DMODEL + n] = v;
        }
      }
    }
}

// ---------------- split-K reducer: out = p0 + p1 + bias + resid --------------
__global__ __launch_bounds__(256) void k_red(const float* __restrict__ p,
                                             const float* __restrict__ bias,
                                             const float* __restrict__ resid,
                                             float* __restrict__ out) {
  int idx = blockIdx.x * 256 + threadIdx.x;
  if (idx >= S_VALID * (DMODEL / 4)) return;
  int m = idx / (DMODEL / 4), n4 = (idx % (DMODEL / 4)) * 4;
  float4 a  = *(const float4*)(p + (size_t)m * DMODEL + n4);
  float4 b  = *(const float4*)(p + ((size_t)S_PAD + m) * DMODEL + n4);
  float4 rs = *(const float4*)(resid + (size_t)m * DMODEL + n4);
  float4 bb = *(const float4*)(bias + n4);
  float4 o;
  o.x = a.x + b.x + rs.x + bb.x;
  o.y = a.y + b.y + rs.y + bb.y;
  o.z = a.z + b.z + rs.z + bb.z;
  o.w = a.w + b.w + rs.w + bb.w;
  *(float4*)(out + (size_t)m * DMODEL + n4) = o;
}

// ---- flash attention, split-KV x2, KVBLK=64 (two verified 32-key subtiles) --
__global__ __launch_bounds__(256) void k_attn(const u16* __restrict__ q,
                                              const u16* __restrict__ k,
                                              const u16* __restrict__ vt,
                                              u16* __restrict__ o0,
                                              u16* __restrict__ o1,
                                              float2* __restrict__ ml) {
  __shared__ __align__(128) u16 kls[2][2][2048];
  __shared__ __align__(128) u16 vls[2][2][2048];
  const int t = threadIdx.x;
  const int lane = t & 63, wid = t >> 6;
  const int h = blockIdx.y, z = blockIdx.z;
  const int zb = z * ZKEYS;
  const int qbase = blockIdx.x * 64 + wid * 16;
  const int l15 = lane & 15, g = lane >> 4;

  const int srow = t >> 3;
  const int psl  = t & 7;
  const int slog = psl ^ (srow & 7);
  const int kperm = 8 * ((srow & 15) >> 2) + (srow & 3) + 4 * (srow >> 4);
  const int vd    = 2 * srow + (slog >> 2);
  const int vkoff = (slog & 3) * 8;
  const u16* kbasep = k + (size_t)kperm * DMODEL + h * HDIM + slog * 8;
  const u16* vbasep = vt + (size_t)(h * HDIM + vd) * S_PAD + vkoff;
  const int wbase = (t >> 6) << 9;

  bf16x8 qf[2];
#pragma unroll
  for (int half = 0; half < 2; ++half)
    qf[half] = *(const bf16x8*)(q + (qbase + l15) * DMODEL + h * HDIM + half * 32 + g * 8);

  auto stage = [&](int tt, int buf) {
#pragma unroll
    for (int u = 0; u < 2; ++u) {
      int keyoff = zb + tt * 64 + u * 32;
      __builtin_amdgcn_global_load_lds(
          (const __attribute__((address_space(1))) void*)(kbasep + (size_t)keyoff * DMODEL),
          (__attribute__((address_space(3))) void*)(&kls[buf][u][0] + wbase), 16, 0, 0);
      __builtin_amdgcn_global_load_lds(
          (const __attribute__((address_space(1))) void*)(vbasep + keyoff),
          (__attribute__((address_space(3))) void*)(&vls[buf][u][0] + wbase), 16, 0, 0);
    }
  };

  stage(0, 0);
  int buf = 0;

  float Mx = -1e30f, L = 0.f;
  f32x4 c[4] = {};

  for (int tt = 0; tt < NSPLIT_TILES; ++tt) {
    if (tt + 1 < NSPLIT_TILES) {
      stage(tt + 1, buf ^ 1);
      wait_vmcnt<4>();
    } else {
      wait_vmcnt<0>();
    }
    __builtin_amdgcn_s_barrier();

    f32x4 sc[2][2];
#pragma unroll
    for (int u = 0; u < 2; ++u)
#pragma unroll
      for (int s = 0; s < 2; ++s) {
        int row = 16 * s + l15;
        const u16* kb = &kls[buf][u][0];
        bf16x8 ka0 = *(const bf16x8*)(kb + row * 64 + ((g)     ^ (row & 7)) * 8);
        bf16x8 ka1 = *(const bf16x8*)(kb + row * 64 + ((4 + g) ^ (row & 7)) * 8);
        f32x4 zz = {};
        zz = __builtin_amdgcn_mfma_f32_16x16x32_bf16(ka0, qf[0], zz, 0, 0, 0);
        zz = __builtin_amdgcn_mfma_f32_16x16x32_bf16(ka1, qf[1], zz, 0, 0, 0);
        sc[u][s] = zz;
      }
    float pm = -1e30f;
#pragma unroll
    for (int u = 0; u < 2; ++u)
#pragma unroll
      for (int s = 0; s < 2; ++s)
#pragma unroll
        for (int r = 0; r < 4; ++r) {
          int kg = zb + tt * 64 + u * 32 + 8 * g + 4 * s + r;
          float v = (kg < S_VALID) ? sc[u][s][r] : -1e30f;
          sc[u][s][r] = v;
          pm = fmaxf(pm, v);
        }
    pm = fmaxf(pm, __shfl_xor(pm, 16));
    pm = fmaxf(pm, __shfl_xor(pm, 32));
    float Mn = fmaxf(Mx, pm);
    float fac = __expf(Mx - Mn);
    float p[2][8]; float rs = 0.f;
#pragma unroll
    for (int u = 0; u < 2; ++u)
#pragma unroll
      for (int s = 0; s < 2; ++s)
#pragma unroll
        for (int r = 0; r < 4; ++r) {
          float e = __expf(sc[u][s][r] - Mn);
          p[u][4 * s + r] = e; rs += e;
        }
    rs += __shfl_xor(rs, 16);
    rs += __shfl_xor(rs, 32);
    L = L * fac + rs; Mx = Mn;

    float facr[4];
#pragma unroll
    for (int r = 0; r < 4; ++r) facr[r] = __shfl(fac, g * 20 + r);
#pragma unroll
    for (int ch = 0; ch < 4; ++ch)
#pragma unroll
      for (int r = 0; r < 4; ++r) c[ch][r] *= facr[r];

    bf16x8 pa[2];
#pragma unroll
    for (int u = 0; u < 2; ++u)
#pragma unroll
      for (int j = 0; j < 8; ++j) pa[u][j] = (short)f2bf(p[u][j]);
#pragma unroll
    for (int ch = 0; ch < 4; ++ch) {
      int R = 8 * ch + (l15 >> 1);
      int sl = (l15 & 1) * 4 + g;
#pragma unroll
      for (int u = 0; u < 2; ++u) {
        bf16x8 vbf = *(const bf16x8*)(&vls[buf][u][0] + R * 64 + (sl ^ (R & 7)) * 8);
        c[ch] = __builtin_amdgcn_mfma_f32_16x16x32_bf16(pa[u], vbf, c[ch], 0, 0, 0);
      }
    }
    __builtin_amdgcn_s_barrier();
    buf ^= 1;
  }

  u16* op = z ? o1 : o0;
  if (g == 0) ml[(size_t)(z * NHEAD + h) * S_PAD + qbase + l15] = make_float2(Mx, L);
#pragma unroll
  for (int ch = 0; ch < 4; ++ch)
#pragma unroll
    for (int r = 0; r < 4; ++r) {
      int m = qbase + g * 4 + r;
      op[(size_t)m * DMODEL + h * HDIM + ch * 16 + l15] = f2bf(c[ch][r]);
    }
}

// ---------------- combine the two KV halves (exact fp32 LSE merge) -----------
__global__ __launch_bounds__(256) void k_comb(u16* __restrict__ o0,
                                              const u16* __restrict__ o1,
                                              const float2* __restrict__ ml) {
  int idx = blockIdx.x * 256 + threadIdx.x;
  if (idx >= S_VALID * (DMODEL / 4)) return;
  int m = idx / (DMODEL / 4);
  int d = (idx % (DMODEL / 4)) * 4;
  int h = d >> 6;
  float2 a = ml[(size_t)h * S_PAD + m];
  float2 b = ml[(size_t)(NHEAD + h) * S_PAD + m];
  float M = fmaxf(a.x, b.x);
  float w0 = __expf(a.x - M), w1 = __expf(b.x - M);
  float inv = 1.f / (w0 * a.y + w1 * b.y);
  w0 *= inv; w1 *= inv;
  union { u16 s[4]; uint2 v; } A, B, O;
  A.v = *(const uint2*)(o0 + (size_t)m * DMODEL + d);
  B.v = *(const uint2*)(o1 + (size_t)m * DMODEL + d);
#pragma unroll
  for (int j = 0; j < 4; ++j)
    O.s[j] = f2bf(w0 * bf2f(A.s[j]) + w1 * bf2f(B.s[j]));
  *(uint2*)(o0 + (size_t)m * DMODEL + d) = O.v;
}

// ----------------------------------------------------------------------------
extern "C" void kernel_launch(void* const* d_in, const int* in_sizes, int n_in,
                              void* d_out, int out_size, void* d_ws, size_t ws_size,
                              hipStream_t stream) {
  const float* x    = (const float*)d_in[0];
  const float* ln1w = (const float*)d_in[1];
  const float* ln1b = (const float*)d_in[2];
  const float* ln2w = (const float*)d_in[3];
  const float* ln2b = (const float*)d_in[4];
  const float* wq   = (const float*)d_in[5];
  const float* qb   = (const float*)d_in[6];
  const float* wk   = (const float*)d_in[7];
  const float* wv   = (const float*)d_in[8];
  const float* vb   = (const float*)d_in[9];
  const float* wo   = (const float*)d_in[10];
  const float* ob   = (const float*)d_in[11];
  const float* wfc1 = (const float*)d_in[12];
  const float* fb1  = (const float*)d_in[13];
  const float* wfc2 = (const float*)d_in[14];
  const float* fb2  = (const float*)d_in[15];

  char* ws = (char*)d_ws;
  size_t off = 0;
  auto alloc = [&](size_t bytes) {
    void* p = ws + off; off += (bytes + 255) & ~(size_t)255; return p;
  };
  u16*   w_qkv = (u16*)alloc((size_t)3 * DMODEL * DMODEL * 2);
  u16*   w_o   = (u16*)alloc((size_t)DMODEL * DMODEL * 2);
  u16*   w_f1  = (u16*)alloc((size_t)FFND * DMODEL * 2);
  u16*   w_f2  = (u16*)alloc((size_t)DMODEL * FFND * 2);
  u16*   hbuf  = (u16*)alloc((size_t)S_PAD * DMODEL * 2);
  u16*   qbuf  = (u16*)alloc((size_t)S_PAD * DMODEL * 2);
  u16*   kbuf  = (u16*)alloc((size_t)S_PAD * DMODEL * 2);
  u16*   vtb   = (u16*)alloc((size_t)DMODEL * S_PAD * 2);
  u16*   ctxb  = (u16*)alloc((size_t)S_PAD * DMODEL * 2);
  float* res2  = (float*)alloc((size_t)S_PAD * DMODEL * 4);
  u16*   h2buf = (u16*)alloc((size_t)S_PAD * DMODEL * 2);
  u16*   gbuf  = (u16*)alloc((size_t)S_PAD * FFND * 2);
  float* skp   = (float*)hbuf;
  u16*    opart1 = (u16*)res2;
  float2* mlbuf  = (float2*)((char*)res2 + (size_t)S_PAD * DMODEL * 2);
  (void)ws_size; (void)n_in; (void)in_sizes; (void)out_size;

  const int nDD = DMODEL * DMODEL;
  const int nF  = FFND * DMODEL;
  k_cvt4<<<dim3(nDD / 1024, 4), 256, 0, stream>>>(
      wq, wk, wv, wo, w_qkv, w_qkv + (size_t)nDD, w_qkv + (size_t)2 * nDD, w_o, nDD);
  k_cvt2<<<dim3(nF / 1024, 2), 256, 0, stream>>>(wfc1, wfc2, w_f1, w_f2, nF);

  // LN1
  k_ln<<<S_PAD, 256, 0, stream>>>(x, ln1w, ln1b, hbuf, S_VALID);

  // QKV GEMM  M=1536 N=3840 K=1280  (64x128/512thr, 720 blocks — R12 best)
  {
    EpiParams ep = {};
    ep.q = qbuf; ep.k = kbuf; ep.vt = vtb; ep.qb = qb; ep.vb = vb; ep.mvalid = S_VALID;
    k_gemm<64, 128, 0><<<dim3(S_PAD / 64, 3 * DMODEL / 128), 512, 0, stream>>>(
        hbuf, w_qkv, 3 * DMODEL, DMODEL, DMODEL, DMODEL, ep);
  }

  // attention: split-KV x2, KVBLK=64  (24 x 20 x 2 = 960 blocks)
  k_attn<<<dim3(S_PAD / 64, NHEAD, 2), 256, 0, stream>>>(
      qbuf, kbuf, vtb, ctxb, opart1, mlbuf);
  k_comb<<<(S_VALID * (DMODEL / 4) + 255) / 256, 256, 0, stream>>>(
      ctxb, opart1, mlbuf);

  // O-proj split-K2 partials  (64x128/512thr, 480 blocks — R12 best)
  {
    EpiParams ep = {};
    ep.outf = skp; ep.mvalid = S_VALID;
    k_gemm<64, 128, 4><<<dim3(S_PAD / 64, DMODEL / 128, 2), 512, 0, stream>>>(
        ctxb, w_o, DMODEL, DMODEL / 2, DMODEL, DMODEL, ep);
  }
  k_red<<<(S_VALID * (DMODEL / 4) + 255) / 256, 256, 0, stream>>>(
      skp, ob, x, res2);

  // LN2
  k_ln<<<S_PAD, 256, 0, stream>>>(res2, ln2w, ln2b, h2buf, S_VALID);

  // FC1 + GELU  (128x128/512thr, 480 blocks — NEW: half the staged bytes/FLOP)
  {
    EpiParams ep = {};
    ep.bias = fb1; ep.outb = gbuf; ep.mvalid = S_VALID;
    k_gemm3<128, 128, 2><<<dim3(S_PAD / 128, FFND / 128), 512, 0, stream>>>(
        h2buf, w_f1, FFND, DMODEL, DMODEL, DMODEL, ep);
  }

  // FC2 split-K2 partials  (128x128/512thr, 240 blocks)  lda = FFND!
  {
    EpiParams ep = {};
    ep.outf = skp; ep.mvalid = S_VALID;
    k_gemm3<128, 128, 4><<<dim3(S_PAD / 128, DMODEL / 128, 2), 512, 0, stream>>>(
        gbuf, w_f2, DMODEL, FFND / 2, FFND, FFND, ep);
  }
  k_red<<<(S_VALID * (DMODEL / 4) + 255) / 256, 256, 0, stream>>>(
      skp, fb2, res2, (float*)d_out);
}